// Round 2
// baseline (433.294 us; speedup 1.0000x reference)
//
#include <hip/hip_runtime.h>

// Problem: B=2,H=16,S=2048,D=128 (f32 I/O; internal bf16 MFMA)
//   qk[q,k] = (x1[q,:]·x2[k,:])*scale + mask[q,k]
//   P = softmax_k(qk);  out[d,k] = sum_q x3[d,q] * P[q,k]
// Softmax stats are per-row(q) over k, contraction is over q -> two passes:
//   K1: rl[q] = 1 / sum_k exp(qk[q,k])   (no max-subtraction: |qk·s+m| < ~11)
//   K2: out = x3 @ (exp(qk) * rl[q])     (E transposed through LDS for B-frag)

typedef __attribute__((ext_vector_type(8))) short short8;
typedef __attribute__((ext_vector_type(4))) float f32x4;

#define S_LEN 2048
#define D_LEN 128
#define BH_N 32
#define SCALE_QK 0.08838834764831845f

__device__ __forceinline__ unsigned short f2bf(float f) {
    union { float f; unsigned int i; } v; v.f = f;
    unsigned int r = v.i + 0x7FFFu + ((v.i >> 16) & 1u);  // RNE
    return (unsigned short)(r >> 16);
}
__device__ __forceinline__ uint2 pack4bf(float4 v) {
    uint2 p;
    p.x = (unsigned)f2bf(v.x) | ((unsigned)f2bf(v.y) << 16);
    p.y = (unsigned)f2bf(v.z) | ((unsigned)f2bf(v.w) << 16);
    return p;
}

// ---------------- Kernel 1: row sums of exp(qk) ----------------
// grid(16, 32): x = 128-row q tile, y = bh. 256 threads (4 waves).
__global__ __launch_bounds__(256, 3) void k_rowsum(
    const float* __restrict__ x1,
    const float* __restrict__ x2,
    const float* __restrict__ mask,
    float* __restrict__ rl)
{
    __shared__ unsigned short sQ[128 * 136];  // q x d (bf16), pad 128->136
    __shared__ unsigned short sK[64 * 136];   // k x d (bf16)
    const int q0 = blockIdx.x * 128;
    const int bh = blockIdx.y;
    const float* x1b = x1 + (size_t)bh * S_LEN * D_LEN;
    const float* x2b = x2 + (size_t)bh * S_LEN * D_LEN;
    const int t = threadIdx.x;
    const int w = t >> 6, lane = t & 63, quad = lane >> 4, l16 = lane & 15;

#pragma unroll
    for (int i = 0; i < 16; ++i) {  // stage x1 tile (128x128), f32 -> bf16
        int e = (i * 256 + t) * 4;
        int r = e >> 7, c = e & 127;
        float4 v = *(const float4*)&x1b[(size_t)(q0 + r) * D_LEN + c];
        *(uint2*)&sQ[r * 136 + c] = pack4bf(v);
    }

    float rs[8] = {0.f, 0.f, 0.f, 0.f, 0.f, 0.f, 0.f, 0.f};

    for (int k0 = 0; k0 < S_LEN; k0 += 64) {
        __syncthreads();  // protect sK from previous iteration's reads
#pragma unroll
        for (int i = 0; i < 8; ++i) {
            int e = (i * 256 + t) * 4;
            int r = e >> 7, c = e & 127;
            float4 v = *(const float4*)&x2b[(size_t)(k0 + r) * D_LEN + c];
            *(uint2*)&sK[r * 136 + c] = pack4bf(v);
        }
        __syncthreads();  // sK (and first-iter sQ) visible
        // wave w owns q rows [32w, 32w+32)
#pragma unroll
        for (int qb = 0; qb < 2; ++qb) {
            const int qrow = 32 * w + 16 * qb;
#pragma unroll
            for (int kb = 0; kb < 4; ++kb) {
                f32x4 acc = {0.f, 0.f, 0.f, 0.f};
#pragma unroll
                for (int kk = 0; kk < 4; ++kk) {
                    short8 a = *(const short8*)&sQ[(qrow + l16) * 136 + kk * 32 + quad * 8];
                    short8 b = *(const short8*)&sK[(kb * 16 + l16) * 136 + kk * 32 + quad * 8];
                    acc = __builtin_amdgcn_mfma_f32_16x16x32_bf16(a, b, acc, 0, 0, 0);
                }
                const int kg = k0 + kb * 16 + l16;       // global k col
                const int qg = q0 + qrow + 4 * quad;     // global q row (base)
#pragma unroll
                for (int r = 0; r < 4; ++r) {
                    float m = mask[(size_t)(qg + r) * S_LEN + kg];
                    rs[qb * 4 + r] += __expf(acc[r] * SCALE_QK + m);
                }
            }
        }
    }
    // reduce across the 16 column-lanes of each quad; write 1/l
#pragma unroll
    for (int i = 0; i < 8; ++i) {
        float v = rs[i];
        v += __shfl_xor(v, 1);
        v += __shfl_xor(v, 2);
        v += __shfl_xor(v, 4);
        v += __shfl_xor(v, 8);
        if (l16 == 0) {
            int qg = q0 + 32 * w + 16 * (i >> 2) + 4 * quad + (i & 3);
            rl[(size_t)bh * S_LEN + qg] = 1.0f / v;
        }
    }
}

// ---------------- Kernel 2: out = x3 @ (exp(qk) * rl) ----------------
// grid(32, 32): x = 64-col k block, y = bh. 256 threads (4 waves).
__global__ __launch_bounds__(256, 2) void k_out(
    const float* __restrict__ x1,
    const float* __restrict__ x2,
    const float* __restrict__ x3,
    const float* __restrict__ mask,
    const float* __restrict__ rl,
    float* __restrict__ out)
{
    __shared__ unsigned short sK[64 * 136];  // x2 k-block (k x d) bf16, resident
    __shared__ unsigned short sQ[64 * 136];  // x1 q-tile  (q x d) bf16
    __shared__ unsigned short sX[128 * 72];  // x3 tile    (d x q) bf16, pad 64->72
    __shared__ unsigned short sE[64 * 72];   // E^T        (k x q) bf16
    const int kb0 = blockIdx.x * 64;
    const int bh = blockIdx.y;
    const float* x1b = x1 + (size_t)bh * S_LEN * D_LEN;
    const float* x2b = x2 + (size_t)bh * S_LEN * D_LEN;
    const float* x3b = x3 + (size_t)bh * (size_t)D_LEN * S_LEN;
    const float* rlb = rl + (size_t)bh * S_LEN;
    const int t = threadIdx.x;
    const int w = t >> 6, lane = t & 63, quad = lane >> 4, l16 = lane & 15;

#pragma unroll
    for (int i = 0; i < 8; ++i) {  // stage resident x2 k-block (64x128)
        int e = (i * 256 + t) * 4;
        int r = e >> 7, c = e & 127;
        float4 v = *(const float4*)&x2b[(size_t)(kb0 + r) * D_LEN + c];
        *(uint2*)&sK[r * 136 + c] = pack4bf(v);
    }

    f32x4 oa[8];  // wave w: d rows [32w,32w+32) x 64 k cols -> 2x4 tiles
#pragma unroll
    for (int i = 0; i < 8; ++i) oa[i] = (f32x4){0.f, 0.f, 0.f, 0.f};

    for (int q0 = 0; q0 < S_LEN; q0 += 64) {
        __syncthreads();  // previous PV reads of sX/sE done; sK staged (iter 0)
#pragma unroll
        for (int i = 0; i < 8; ++i) {  // stage x1 q-tile (64x128)
            int e = (i * 256 + t) * 4;
            int r = e >> 7, c = e & 127;
            float4 v = *(const float4*)&x1b[(size_t)(q0 + r) * D_LEN + c];
            *(uint2*)&sQ[r * 136 + c] = pack4bf(v);
        }
#pragma unroll
        for (int i = 0; i < 8; ++i) {  // stage x3 tile (128 d x 64 q)
            int e = (i * 256 + t) * 4;
            int r = e >> 6, c = e & 63;
            float4 v = *(const float4*)&x3b[(size_t)r * S_LEN + q0 + c];
            *(uint2*)&sX[r * 72 + c] = pack4bf(v);
        }
        __syncthreads();

        // QK: wave w owns q rows [16w, 16w+16)
        const int qrow = 16 * w + 4 * quad;  // C-layout row base
        float rl4[4];
#pragma unroll
        for (int r = 0; r < 4; ++r) rl4[r] = rlb[q0 + qrow + r];
#pragma unroll
        for (int kb = 0; kb < 4; ++kb) {
            f32x4 acc = {0.f, 0.f, 0.f, 0.f};
#pragma unroll
            for (int kk = 0; kk < 4; ++kk) {
                short8 a = *(const short8*)&sQ[(16 * w + l16) * 136 + kk * 32 + quad * 8];
                short8 b = *(const short8*)&sK[(kb * 16 + l16) * 136 + kk * 32 + quad * 8];
                acc = __builtin_amdgcn_mfma_f32_16x16x32_bf16(a, b, acc, 0, 0, 0);
            }
            const int kg = kb0 + kb * 16 + l16;
            unsigned short e4[4];
#pragma unroll
            for (int r = 0; r < 4; ++r) {
                float m = mask[(size_t)(q0 + qrow + r) * S_LEN + kg];
                e4[r] = f2bf(__expf(acc[r] * SCALE_QK + m) * rl4[r]);
            }
            uint2 pk;
            pk.x = (unsigned)e4[0] | ((unsigned)e4[1] << 16);
            pk.y = (unsigned)e4[2] | ((unsigned)e4[3] << 16);
            // E^T[k][q]: consecutive q (reg idx) contiguous -> one b64 write
            *(uint2*)&sE[(kb * 16 + l16) * 72 + qrow] = pk;
        }
        __syncthreads();

        // PV: out[d, k] += sum_q x3[d,q] * E[q,k]
#pragma unroll
        for (int db = 0; db < 2; ++db) {
#pragma unroll
            for (int kb = 0; kb < 4; ++kb) {
                f32x4 a0 = oa[db * 4 + kb];
#pragma unroll
                for (int kk = 0; kk < 2; ++kk) {
                    short8 a = *(const short8*)&sX[(32 * w + 16 * db + l16) * 72 + kk * 32 + quad * 8];
                    short8 b = *(const short8*)&sE[(kb * 16 + l16) * 72 + kk * 32 + quad * 8];
                    a0 = __builtin_amdgcn_mfma_f32_16x16x32_bf16(a, b, a0, 0, 0, 0);
                }
                oa[db * 4 + kb] = a0;
            }
        }
    }

    // epilogue: out[b,h,d,k] (f32)
#pragma unroll
    for (int db = 0; db < 2; ++db) {
#pragma unroll
        for (int kb = 0; kb < 4; ++kb) {
#pragma unroll
            for (int r = 0; r < 4; ++r) {
                int d = 32 * w + 16 * db + 4 * quad + r;
                out[((size_t)bh * D_LEN + d) * S_LEN + kb0 + kb * 16 + l16] =
                    oa[db * 4 + kb][r];
            }
        }
    }
}

extern "C" void kernel_launch(void* const* d_in, const int* in_sizes, int n_in,
                              void* d_out, int out_size, void* d_ws, size_t ws_size,
                              hipStream_t stream) {
    const float* x1 = (const float*)d_in[0];
    const float* x2 = (const float*)d_in[1];
    const float* x3 = (const float*)d_in[2];
    const float* mask = (const float*)d_in[3];
    float* rl = (float*)d_ws;  // BH*S f32 = 256 KB
    float* out = (float*)d_out;

    k_rowsum<<<dim3(S_LEN / 128, BH_N), dim3(256), 0, stream>>>(x1, x2, mask, rl);
    k_out<<<dim3(S_LEN / 64, BH_N), dim3(256), 0, stream>>>(x1, x2, x3, mask, rl, out);
}